// Round 1
// baseline (219.709 us; speedup 1.0000x reference)
//
#include <hip/hip_runtime.h>

// out[s,a] = values[index[s,a]]
// index: 16384*2048 int32 (128 MiB), values: 100 fp32 (400 B), out: fp32 (128 MiB)
// Irreducible traffic: 268.4 MB -> ~43 us floor @ 6.29 TB/s measured copy ceiling.
// Bench dur_us (~217.7) = 2 harness re-poison fills (~160 us, untouchable) + kernel (~57 us).
//
// R6: amortize per-block overhead, which is the gap between 57 us and the ~43 us floor:
//  - 4 int4 per thread (64 B/lane), flat unrolled (R4: flat beats grid-stride):
//    2048 blocks instead of 8192 -> 4x fewer block prologues (8 blocks/CU, 4 rounds of 2).
//  - per-wave private LDS value tables (16 waves x 128 floats = 8 KB): wave-local
//    s_waitcnt lgkmcnt(0) replaces the 16-wave __syncthreads() -> no cross-wave
//    barrier convoying before streaming starts. Bank layout per table identical
//    (100 floats span all 32 banks), so gather conflict cost is unchanged.
//  - vals load issued before idx loads: vmcnt retires in order, so the LDS table
//    write only waits for vals while the 4 idx loads remain in flight.

constexpr int VOCAB = 100;

typedef int   vint4   __attribute__((ext_vector_type(4)));
typedef float vfloat4 __attribute__((ext_vector_type(4)));

__global__ __launch_bounds__(1024) void gather_kernel(
    const vint4* __restrict__ idx4,
    const float* __restrict__ vals,
    vfloat4* __restrict__ out4)
{
    __shared__ float svals[16 * 128];   // one 128-float slot per wave (8 KB)

    const int lane = threadIdx.x & 63;
    const int wid  = threadIdx.x >> 6;
    float* wt = &svals[wid * 128];

    // Load the value table (global, L1-hot after first block). Issue before idx
    // loads in program order so its vmcnt retires first.
    float v_lo = vals[lane];                                   // vals[0..63]
    float v_hi = (lane < VOCAB - 64) ? vals[64 + lane] : 0.f;  // vals[64..99]

    // Flat addressing: thread t owns int4s {t, t+1024, t+2048, t+3072} within
    // its block's 4096-int4 span -> every load/store instruction is 64
    // consecutive int4s = 1 KiB fully coalesced.
    const int t = blockIdx.x * 4096 + threadIdx.x;

    vint4 v0 = __builtin_nontemporal_load(&idx4[t]);
    vint4 v1 = __builtin_nontemporal_load(&idx4[t + 1024]);
    vint4 v2 = __builtin_nontemporal_load(&idx4[t + 2048]);
    vint4 v3 = __builtin_nontemporal_load(&idx4[t + 3072]);

    // Per-wave table fill; wave-local visibility only needs lgkmcnt(0),
    // no __syncthreads (each wave reads exclusively its own 128-float slot).
    wt[lane] = v_lo;
    if (lane < VOCAB - 64) wt[64 + lane] = v_hi;
    asm volatile("s_waitcnt lgkmcnt(0)" ::: "memory");

    vfloat4 o0 = { wt[v0.x], wt[v0.y], wt[v0.z], wt[v0.w] };
    __builtin_nontemporal_store(o0, &out4[t]);
    vfloat4 o1 = { wt[v1.x], wt[v1.y], wt[v1.z], wt[v1.w] };
    __builtin_nontemporal_store(o1, &out4[t + 1024]);
    vfloat4 o2 = { wt[v2.x], wt[v2.y], wt[v2.z], wt[v2.w] };
    __builtin_nontemporal_store(o2, &out4[t + 2048]);
    vfloat4 o3 = { wt[v3.x], wt[v3.y], wt[v3.z], wt[v3.w] };
    __builtin_nontemporal_store(o3, &out4[t + 3072]);
}

extern "C" void kernel_launch(void* const* d_in, const int* in_sizes, int n_in,
                              void* d_out, int out_size, void* d_ws, size_t ws_size,
                              hipStream_t stream) {
    const int*   idx  = (const int*)d_in[0];     // 16384*2048 int32
    const float* vals = (const float*)d_in[1];   // 100 fp32
    float*       out  = (float*)d_out;           // fp32

    int n  = in_sizes[0];                        // 33554432
    int n4 = n / 4;                              // 8388608 int4s

    const int block = 1024;
    const int per_block = block * 4;             // 4096 int4s per block
    const int grid  = n4 / per_block;            // 2048 blocks, exact cover

    gather_kernel<<<grid, block, 0, stream>>>(
        (const vint4*)idx, vals, (vfloat4*)out);
}

// Round 2
// 218.953 us; speedup vs baseline: 1.0035x; 1.0035x over previous
//
#include <hip/hip_runtime.h>

// out[s,a] = values[index[s,a]]
// index: 16384*2048 int32 (128 MiB), values: 100 fp32 (400 B), out: fp32 (128 MiB)
// Irreducible kernel traffic: 268.4 MB. Timed iteration = 2 harness fills
// (2x536.9 MB, ~160 us, untouchable) + kernel (~57 us @ ~4.7 TB/s).
// Aggregate iteration BW: 1342 MB / 217.7 us = 6.17 TB/s = 98% of copy ceiling.
//
// R7: single-variable A/B vs R5 baseline (217.3 us): remove the nontemporal
// hint from the STORE only. Rationale: nt stores bypass L2/L3 write
// allocation; the 134 MB output fits the 256 MiB L3, so plain stores let L3
// absorb write bursts and drain concurrently with the read stream -- this is
// the one structural difference from the 6.29 TB/s copy microbenchmark.
// Everything else identical to R5 (1 int4/thread, block=1024, grid=8192,
// nt load kept: streaming read, no reuse either way).
// R6 post-mortem: 4 int4/thread + per-wave tables + no __syncthreads = +2.0 us
// (noise) -> block prologue/barrier overhead is NOT the bottleneck; plateau
// is a memory-system property of the R/W mix.

constexpr int VOCAB = 100;

typedef int   vint4   __attribute__((ext_vector_type(4)));
typedef float vfloat4 __attribute__((ext_vector_type(4)));

__global__ __launch_bounds__(1024) void gather_kernel(
    const vint4* __restrict__ idx4,
    const float* __restrict__ vals,
    vfloat4* __restrict__ out4)
{
    __shared__ float svals[VOCAB];
    if (threadIdx.x < VOCAB) svals[threadIdx.x] = vals[threadIdx.x];
    __syncthreads();

    const int t = blockIdx.x * blockDim.x + threadIdx.x;  // one int4 per thread

    vint4 v = __builtin_nontemporal_load(&idx4[t]);
    vfloat4 o = { svals[v.x], svals[v.y], svals[v.z], svals[v.w] };
    out4[t] = o;   // plain store: L2/L3 write-allocate, let L3 absorb the burst
}

extern "C" void kernel_launch(void* const* d_in, const int* in_sizes, int n_in,
                              void* d_out, int out_size, void* d_ws, size_t ws_size,
                              hipStream_t stream) {
    const int*   idx  = (const int*)d_in[0];     // 16384*2048 int32
    const float* vals = (const float*)d_in[1];   // 100 fp32
    float*       out  = (float*)d_out;           // fp32

    int n  = in_sizes[0];                        // 33554432 (divisible by 4)
    int n4 = n / 4;                              // 8388608 = 8192 * 1024

    const int block = 1024;
    const int grid  = n4 / block;                // 8192 blocks, exact cover

    gather_kernel<<<grid, block, 0, stream>>>(
        (const vint4*)idx, vals, (vfloat4*)out);
}